// Round 14
// baseline (1219.660 us; speedup 1.0000x reference)
//
#include <hip/hip_runtime.h>
#include <stdint.h>

typedef _Float16 half8 __attribute__((ext_vector_type(8)));
typedef float float4v __attribute__((ext_vector_type(4)));

#define H_IN 256
#define W_IN 256
#define H_OUT 254
#define W_OUT 254
#define T_COLS 68
#define T_INROWS 8
#define A_ROWS (T_INROWS * T_COLS)   // 544 LDS rows of 128 B
#define A_BYTES (A_ROWS * 128)       // 69632
#define SMEM_BYTES (2 * A_BYTES)     // 139264 (dbuf)
#define N_TILES 43                   // ceil(254/6)

// ---------------------------------------------------------------------------
// Pack conv_weight (OIHW fp32) into coalesced-fragment layout (v5 layout):
//   Bp2[g][co][q][e], g=(kh*3+kw)*2+h, cin=h*32+q*8+e. 1KB contiguous/frag.
// ---------------------------------------------------------------------------
__global__ void pack_w_kernel(const float* __restrict__ w, _Float16* __restrict__ Bp2) {
    int idx = blockIdx.x * 256 + threadIdx.x;          // 128*576 = 73728
    if (idx >= 128 * 576) return;
    int co  = idx / 576;
    int kp  = idx - co * 576;
    int tap = kp >> 6;
    int cin = kp & 63;
    int kh  = tap / 3, kw = tap - kh * 3;
    int h   = cin >> 5;
    int q   = (cin >> 3) & 3;
    int e   = cin & 7;
    int g   = tap * 2 + h;
    Bp2[((((size_t)g * 128 + co) * 4) + q) * 8 + e] =
        (_Float16)w[(co * 64 + cin) * 9 + kh * 3 + kw];
}

__device__ __forceinline__ int akey(int row) {
    return (((row & 7) ^ ((row >> 3) & 7)) << 4);
}

// ---------------------------------------------------------------------------
// v14: LDS-traffic-minimal geometry + persistent A-dbuf.
// 256 thr = 4 waves x 96px x 128co (6m x 8n, acc=192) at 1 wave/SIMD
// (launch_bounds(256,1): 512-reg budget -> prefetch actually fits).
// B direct from L2/L1 (no LDS); LDS reads/group/CU = 24 (288 cyc) << MFMA
// (192 MFMA = 931 cyc/CU): first MFMA-dominated structure.
// n spans all 128 co -> channel-min wave-local -> no cross-wave epilogue.
// Persistent: grid (4,4,16) = 1 block/CU, each walks ~11 tiles of 6 out-rows;
// next tile staged (fp32 load -> cvt -> swizzled ds_write) during groups 6-16
// into the other A buffer; ONE __syncthreads per tile; no manual vmcnt.
// ---------------------------------------------------------------------------
__global__ __launch_bounds__(256, 1)
void conv_v14_kernel(const float* __restrict__ x,
                     const _Float16* __restrict__ Bp2,
                     const float* __restrict__ bias,
                     float* __restrict__ out) {
    extern __shared__ __align__(16) char smem[];   // [2][A_BYTES]

    const int tid  = threadIdx.x;
    const int lane = tid & 63;
    const int wave = tid >> 6;      // 0..3
    const int ow0  = blockIdx.x * 64;
    const int by   = blockIdx.y;    // 0..3: tiles ty = by, by+4, ...
    const int nb   = blockIdx.z;
    const int q    = lane >> 4;
    const int lr   = lane & 15;
    const int pxb  = wave * 96;     // wave's first pixel in the 384-px tile

    const float* xb  = x + (size_t)nb * (64 * H_IN * W_IN);
    const char*  bp0 = (const char*)Bp2 + lr * 64 + q * 16;
    float*       ob  = out + (size_t)nb * (H_OUT * W_OUT);

    float bv[8];
#pragma unroll
    for (int n = 0; n < 8; ++n) bv[n] = bias[n * 16 + lr];

    // ---- staging: 1088 items (8 in-rows x 17 col-quads x 8 cin-octs)
    float4v f0[8], f1[8];
    auto s_load = [&](int c, int ih0, float4v (&f)[8]) {
        int id = tid + (c << 8); if (id > 1087) id = 1087;   // dup-load, no write
        int pxq = id >> 3, oct = id & 7;
        int r   = (unsigned)pxq / 17u;
        int q4  = pxq - r * 17;
        int ih  = ih0 + r; if (ih > H_IN - 1) ih = H_IN - 1;
        int iw  = ow0 + q4 * 4; if (iw > W_IN - 4) iw = W_IN - 4;
        const float* src = xb + (size_t)(oct * 8) * (H_IN * W_IN)
                              + (size_t)ih * W_IN + iw;
#pragma unroll
        for (int u = 0; u < 8; ++u)
            f[u] = *(const float4v*)(src + (size_t)u * (H_IN * W_IN));
    };
    auto s_write = [&](int c, char* abuf, float4v (&f)[8]) {
        int id = tid + (c << 8);
        if (id < 1088) {
            int pxq = id >> 3, oct = id & 7;
            int row0 = pxq * 4;
#pragma unroll
            for (int j = 0; j < 4; ++j) {
                int row = row0 + j;
                half8 hv;
#pragma unroll
                for (int u = 0; u < 8; ++u) hv[u] = (_Float16)f[u][j];
                *(half8*)(abuf + row * 128 + ((oct * 16) ^ akey(row))) = hv;
            }
        }
    };

    // ---- fragment loaders (g unroll-constant at all call sites)
    half8 aC[6], aN[6], bC[8], bN[8];
    auto loadA = [&](int g, const char* abuf, half8 (&d)[6]) {
        const int tap = g >> 1, hh = g & 1;
        const int kh = tap / 3, kw = tap - kh * 3;
        const int kb = hh * 64 + q * 16;
#pragma unroll
        for (int m = 0; m < 6; ++m) {
            int bpx = pxb + m * 16;
            int row = ((bpx >> 6) + kh) * T_COLS + (bpx & 63) + kw + lr;
            d[m] = *(const half8*)(abuf + row * 128 + (kb ^ akey(row)));
        }
    };
    auto loadB = [&](int g, half8 (&d)[8]) {
#pragma unroll
        for (int n = 0; n < 8; ++n)
            d[n] = *(const half8*)(bp0 + (size_t)g * 8192 + n * 1024);
    };

    // ---- prologue: stage first tile into buf 0 (serial, once)
    {
        int ih0 = 6 * by;
#pragma unroll
        for (int c = 0; c < 5; ++c) { s_load(c, ih0, f0); s_write(c, smem, f0); }
    }
    __syncthreads();

    int par = 0;
    for (int ty = by; ty < N_TILES; ty += 4) {
        char* abuf = smem + par * A_BYTES;
        char* nbuf = smem + (par ^ 1) * A_BYTES;
        const int  oh0  = ty * 6;
        const bool more = (ty + 4) < N_TILES;
        const int  ihn  = (ty + 4) * 6;

        float4v acc[6][8];
#pragma unroll
        for (int m = 0; m < 6; ++m)
#pragma unroll
            for (int n = 0; n < 8; ++n)
#pragma unroll
                for (int i = 0; i < 4; ++i) acc[m][n][i] = 0.0f;

        loadA(0, abuf, aC);
        loadB(0, bC);

#pragma unroll
        for (int g = 0; g < 18; ++g) {
            // depth-1 prefetch of group g+1 into the other named set
            if (g < 17) {
                if (g & 1) { loadB(g + 1, bC); loadA(g + 1, abuf, aC); }
                else       { loadB(g + 1, bN); loadA(g + 1, abuf, aN); }
                __builtin_amdgcn_sched_group_barrier(0x020, 8, 0);  // 8 B loads
                __builtin_amdgcn_sched_group_barrier(0x100, 6, 0);  // 6 A reads
            }

            half8 (&A)[6] = (g & 1) ? aN : aC;
            half8 (&B)[8] = (g & 1) ? bN : bC;
#pragma unroll
            for (int m = 0; m < 6; ++m)
#pragma unroll
                for (int n = 0; n < 8; ++n)
                    acc[m][n] = __builtin_amdgcn_mfma_f32_16x16x32_f16(
                        A[m], B[n], acc[m][n], 0, 0, 0);
            __builtin_amdgcn_sched_group_barrier(0x8, 48, 0);       // 48 MFMA

            // 2-deep chunked staging of next tile (issue-early / write-late)
            if (more) {
                if (g == 6)  { s_load(0, ihn, f0); }
                if (g == 8)  { s_load(1, ihn, f1); }
                if (g == 9)  { s_write(0, nbuf, f0); }
                if (g == 10) { s_load(2, ihn, f0); }
                if (g == 11) { s_write(1, nbuf, f1); }
                if (g == 12) { s_load(3, ihn, f1); }
                if (g == 13) { s_write(2, nbuf, f0); }
                if (g == 14) { s_load(4, ihn, f0); }
                if (g == 15) { s_write(3, nbuf, f1); }
                if (g == 16) { s_write(4, nbuf, f0); }
                if (g == 6 || g == 8 || (g >= 9 && g <= 16))
                    __builtin_amdgcn_sched_barrier(0);
            }
        }

        // ---- epilogue: + bias, min over all 128 channels (8 n-frags + 16
        // lanes), double tanh, direct global store (no LDS, no cross-wave)
#pragma unroll
        for (int m = 0; m < 6; ++m) {
            float4v v;
#pragma unroll
            for (int n = 0; n < 8; ++n) {
#pragma unroll
                for (int i = 0; i < 4; ++i) {
                    float t = acc[m][n][i] + bv[n];
                    v[i] = (n == 0) ? t : fminf(v[i], t);
                }
            }
#pragma unroll
            for (int off = 1; off < 16; off <<= 1)
#pragma unroll
                for (int i = 0; i < 4; ++i)
                    v[i] = fminf(v[i], __shfl_xor(v[i], off, 64));
            if (lr == 0) {
                int bpx = pxb + m * 16 + q * 4;       // q*4+i = row-in-frag
                int oh  = oh0 + (bpx >> 6);
                int owb = ow0 + (bpx & 63);
                if (oh < H_OUT) {
                    float* dst = ob + (size_t)oh * W_OUT + owb;
#pragma unroll
                    for (int i = 0; i < 4; ++i) {
                        if (owb + i < W_OUT)
                            dst[i] = tanhf(tanhf(v[i]));
                    }
                }
            }
        }

        __syncthreads();   // staging writes visible; abuf free for re-stage
        par ^= 1;
    }
}

extern "C" void kernel_launch(void* const* d_in, const int* in_sizes, int n_in,
                              void* d_out, int out_size, void* d_ws, size_t ws_size,
                              hipStream_t stream) {
    const float* x    = (const float*)d_in[0];
    const float* w    = (const float*)d_in[1];
    const float* bias = (const float*)d_in[2];
    float* out        = (float*)d_out;
    _Float16* Bp2     = (_Float16*)d_ws;   // 147456 B

    static bool attr_set = false;   // host-side attribute, idempotent
    if (!attr_set) {
        hipFuncSetAttribute((const void*)conv_v14_kernel,
                            hipFuncAttributeMaxDynamicSharedMemorySize, SMEM_BYTES);
        attr_set = true;
    }

    pack_w_kernel<<<dim3(288), dim3(256), 0, stream>>>(w, Bp2);
    conv_v14_kernel<<<dim3(4, 4, 16), dim3(256), SMEM_BYTES, stream>>>(x, Bp2, bias, out);
}